// Round 12
// baseline (369.384 us; speedup 1.0000x reference)
//
#include <hip/hip_runtime.h>

#define NN   100000
#define NE   1600000
#define NB   400000     // NN*4 (dst,rel) segments
#define EPS  1e-10f

#define NPB   32        // nodes per block
#define NCHK  256       // edge chunks (phase A blocks)
#define EPC   6250      // NE / NCHK
#define NBUCK 391       // coarse buckets: dst>>8  (ceil(100000/256))
#define NHBC  (NBUCK * NCHK)   // 100096
#define NSCAN (NB + NHBC)      // 500096 fused scan length
#define NBLK_FUSED 489         // ceil(NSCAN/1024)

typedef __attribute__((ext_vector_type(8))) short bfrag8;
typedef __attribute__((ext_vector_type(4))) float f4acc;

__device__ __forceinline__ unsigned short f2bf(float f) {
    union { float f; unsigned u; } v; v.f = f;
    unsigned r = v.u + 0x7FFF + ((v.u >> 16) & 1);
    return (unsigned short)(r >> 16);
}
__device__ __forceinline__ float bf2f(unsigned short b) {
    union { unsigned u; float f; } v; v.u = ((unsigned)b) << 16;
    return v.f;
}

// ---------------------------------------------------------------------------
// Phase A1: per-(bucket,chunk) histogram in LDS  +  400K segment histogram
// ---------------------------------------------------------------------------
__global__ __launch_bounds__(256) void kA1(
    const int* __restrict__ dst, const int* __restrict__ rel,
    int* __restrict__ cnt_seg, int* __restrict__ histBC)
{
    __shared__ int s_h[NBUCK];
    for (int i = threadIdx.x; i < NBUCK; i += 256) s_h[i] = 0;
    __syncthreads();
    int e0 = blockIdx.x * EPC;
    for (int e = e0 + threadIdx.x; e < e0 + EPC; e += 256) {
        int d = dst[e];
        atomicAdd(&s_h[d >> 8], 1);
        atomicAdd(&cnt_seg[d * 4 + rel[e]], 1);
    }
    __syncthreads();
    for (int i = threadIdx.x; i < NBUCK; i += 256)
        histBC[i * NCHK + blockIdx.x] = s_h[i];   // bucket-major
}

// --- generic coalesced 3-phase scan ----------------------------------------
__global__ __launch_bounds__(1024) void k_scan_local_g(
    const int* __restrict__ in, int* __restrict__ out,
    int* __restrict__ blksum, int n)
{
    __shared__ int s[1024];
    int t = threadIdx.x;
    int i = blockIdx.x * 1024 + t;
    int v = (i < n) ? in[i] : 0;
    s[t] = v;
    __syncthreads();
    #pragma unroll
    for (int off = 1; off < 1024; off <<= 1) {
        int u = (t >= off) ? s[t - off] : 0;
        __syncthreads();
        s[t] += u;
        __syncthreads();
    }
    if (i < n) out[i] = s[t] - v;
    if (t == 1023) blksum[blockIdx.x] = s[t];
}

__global__ __launch_bounds__(512) void k_scan_blk_g(
    int* __restrict__ blksum, int* __restrict__ blkoff, int nblk)
{
    __shared__ int s[512];
    int t = threadIdx.x;
    int v = (t < nblk) ? blksum[t] : 0;
    s[t] = v;
    __syncthreads();
    #pragma unroll
    for (int off = 1; off < 512; off <<= 1) {
        int u = (t >= off) ? s[t - off] : 0;
        __syncthreads();
        s[t] += u;
        __syncthreads();
    }
    if (t < nblk) blkoff[t] = s[t] - v;
}

__global__ __launch_bounds__(1024) void k_scan_add_g(
    int* __restrict__ out, const int* __restrict__ blkoff, int n)
{
    int i = blockIdx.x * 1024 + threadIdx.x;
    if (i < n) out[i] += blkoff[blockIdx.x];
}

// ---------------------------------------------------------------------------
// Phase A3: partition edges into coarse buckets (line-dense writes).
// chunkOff entries carry a +NE bias from the fused scan; subtract here.
// ---------------------------------------------------------------------------
__global__ __launch_bounds__(256) void kA3(
    const int* __restrict__ src, const int* __restrict__ dst,
    const int* __restrict__ rel, const float* __restrict__ ew,
    const int* __restrict__ chunkOff, int2* __restrict__ pA)
{
    __shared__ int s_c[NBUCK];
    for (int i = threadIdx.x; i < NBUCK; i += 256)
        s_c[i] = chunkOff[i * NCHK + blockIdx.x] - NE;
    __syncthreads();
    int e0 = blockIdx.x * EPC;
    for (int e = e0 + threadIdx.x; e < e0 + EPC; e += 256) {
        int d = dst[e], r = rel[e];
        int pos = atomicAdd(&s_c[d >> 8], 1);
        int2 v;
        v.x = src[e] | (((d & 255) * 4 + r) << 20);
        v.y = __float_as_int(ew[e]);
        pA[pos] = v;
    }
}

// ---------------------------------------------------------------------------
// Phase B: one block per bucket; in-bucket counting sort by seg_local.
// ---------------------------------------------------------------------------
__global__ __launch_bounds__(256) void kB(
    const int* __restrict__ row_ptr, const int2* __restrict__ pA,
    int2* __restrict__ edat)
{
    __shared__ int s_c[1024];
    __shared__ int s_p[256];
    const int b    = blockIdx.x;
    const int t    = threadIdx.x;
    const int seg0 = b * 1024;
    const int segN = min(1024, NB - seg0);
    const int pbeg = row_ptr[seg0];
    const int pend = row_ptr[seg0 + segN];

    for (int i = t; i < 1024; i += 256) s_c[i] = 0;
    __syncthreads();
    for (int p = pbeg + t; p < pend; p += 256)
        atomicAdd(&s_c[((unsigned)pA[p].x) >> 20], 1);
    __syncthreads();

    int c0 = s_c[t * 4], c1 = s_c[t * 4 + 1], c2 = s_c[t * 4 + 2], c3 = s_c[t * 4 + 3];
    int tsum = c0 + c1 + c2 + c3;
    s_p[t] = tsum;
    __syncthreads();
    #pragma unroll
    for (int off = 1; off < 256; off <<= 1) {
        int u = (t >= off) ? s_p[t - off] : 0;
        __syncthreads();
        s_p[t] += u;
        __syncthreads();
    }
    int base = s_p[t] - tsum;
    s_c[t * 4]     = base;
    s_c[t * 4 + 1] = base + c0;
    s_c[t * 4 + 2] = base + c0 + c1;
    s_c[t * 4 + 3] = base + c0 + c1 + c2;
    __syncthreads();

    for (int p = pbeg + t; p < pend; p += 256) {
        int2 v = pA[p];
        int sl = ((unsigned)v.x) >> 20;
        int pos = atomicAdd(&s_c[sl], 1);
        int2 o; o.x = v.x & 0xFFFFF; o.y = v.y;
        edat[pbeg + pos] = o;
    }
    // 192 zero pad entries: layer kernel over-reads meta up to NE+~160
    if (b == 0 && t < 192) { int2 z; z.x = 0; z.y = 0; edat[NE + t] = z; }
}

// ---------------------------------------------------------------------------
// Conversions
// ---------------------------------------------------------------------------
__global__ __launch_bounds__(256) void k_cvt_x(
    const float* __restrict__ xf, unsigned short* __restrict__ xb)
{
    int i = blockIdx.x * 256 + threadIdx.x;
    if (i < NN * 64) xb[i] = f2bf(xf[i]);
}

__global__ __launch_bounds__(256) void k_cvt_w(
    const float* __restrict__ lin_w, const float* __restrict__ self_w,
    const float* __restrict__ pw, const float* __restrict__ tw,
    unsigned short* __restrict__ WL, unsigned short* __restrict__ WP,
    unsigned short* __restrict__ WT2)
{
    int id = blockIdx.x * 256 + threadIdx.x;   // 3*64*576
    if (id >= 3 * 64 * 576) return;
    int i = id / (64 * 576);
    int r = id % (64 * 576);
    int j = r / 576;
    int k = r % 576;
    if (k < 320) {
        float v = (k < 256) ? lin_w[((size_t)i * 256 + k) * 64 + j]
                            : self_w[((size_t)i * 64 + (k - 256)) * 64 + j];
        WL[((size_t)i * 64 + j) * 320 + k] = f2bf(v);
    } else if (k < 448) {
        int kk = k - 320;
        WP[((size_t)i * 64 + j) * 128 + kk] = f2bf(pw[((size_t)i * 128 + kk) * 64 + j]);
    } else {
        int kk = k - 448;
        WT2[((size_t)i * 64 + j) * 128 + kk] = f2bf(tw[((size_t)i * 128 + kk) * 64 + j]);
    }
}

// ---------------------------------------------------------------------------
// Edge-stream helpers: meta read via UNIFORM address (scalar e + literal j)
// -> backend scalarizes to s_load_dwordx* (SMEM, no VALU slots, data->SGPR).
// ---------------------------------------------------------------------------
template<int LBASE>
__device__ __forceinline__ void gather16(
    unsigned short (&g)[16], const int2* __restrict__ mp,
    const unsigned short* __restrict__ xb, int lane)
{
    #pragma unroll
    for (int j = 0; j < 16; ++j) {
        int sm = mp[LBASE + j].x;                     // uniform -> SGPR
        g[j] = xb[((size_t)(unsigned)sm << 6) + lane]; // saddr-form gather
    }
}

template<int LBASE, bool CHECK>
__device__ __forceinline__ void consume16(
    const unsigned short (&g)[16], const int2* __restrict__ mp, int ebase,
    int E1, int& seg, int& segEnd,
    float& acc, float& dsum,
    const int* sRP, int sbase, int wid, int lane, char* sAp)
{
    #pragma unroll
    for (int j = 0; j < 16; ++j) {
        int eidx = ebase + j;                          // scalar
        if (!CHECK || eidx < E1) {                     // s_cmp path (tail only)
            while (eidx >= segEnd) {                   // flush finished segments
                float u = acc * __builtin_amdgcn_rcpf(dsum + EPS);
                int ln = wid * 8 + (seg >> 2);
                int cb = ((seg & 3) * 64 + lane) * 2;
                *(unsigned short*)(sAp + ln * 640 + (cb ^ ((ln & 7) << 4))) = f2bf(u);
                acc = 0.f; dsum = 0.f;
                ++seg;
                segEnd = __builtin_amdgcn_readfirstlane(sRP[sbase + seg + 1]);
            }
            float w = __int_as_float(mp[LBASE + j].y); // uniform -> SGPR
            acc = fmaf(bf2f(g[j]), w, acc);
            dsum += w;
        }
    }
}

// ---------------------------------------------------------------------------
// Fused layer: 32 nodes/block, 4 waves; wave aggregates 8 nodes (32 segs),
// then computes its 16-col tile over 2 row-tiles in the MFMA phases.
// ---------------------------------------------------------------------------
__global__ __launch_bounds__(256, 5) void k_layer(
    const unsigned short* __restrict__ xb,     // layer input bf16 [NN][64]
    const unsigned short* __restrict__ prevb,  // prev hidden bf16 [NN][64]
    const int* __restrict__ row_ptr,
    const int2* __restrict__ edat,
    const unsigned short* __restrict__ WL,     // [64][320]
    const unsigned short* __restrict__ WP,     // [64][128]
    const unsigned short* __restrict__ WT2,    // [64][128]
    const float* __restrict__ lin_b, const float* __restrict__ self_b,
    const float* __restrict__ pb, const float* __restrict__ tb,
    unsigned short* __restrict__ hidb,
    unsigned short* __restrict__ gatedb,
    float* __restrict__ outf,
    int last)
{
    __shared__ __align__(16) unsigned short sA[NPB * 320];  // 20480 B
    __shared__ __align__(16) unsigned short sH[NPB * 128];  //  8192 B
    __shared__ int sRP[NPB * 4 + 1];                        // 129 entries

    const int tid  = threadIdx.x;
    const int lane = tid & 63;
    const int wid  = tid >> 6;
    const int n0   = blockIdx.x * NPB;
    const int bcol = wid * 16 + (lane & 15);
    const int koff2 = (lane >> 4) * 16;
    const int arow = lane & 15;
    const int hi   = lane >> 4;

    if (tid < NPB * 4 + 1) sRP[tid] = row_ptr[n0 * 4 + tid];

    // ---- vectorized staging: 16 B per thread per tile ----
    {
        int r  = tid >> 3;            // 0..31
        int c0 = (tid & 7) * 8;       // 0,8,...,56
        uint4 pv = *(const uint4*)&prevb[(size_t)(n0 + r) * 64 + c0];
        int swz = (r & 7) << 4;
        *(uint4*)((char*)sH + r * 256 + (((64 + c0) * 2) ^ swz)) = pv;
        uint4 xv = *(const uint4*)&xb[(size_t)(n0 + r) * 64 + c0];
        *(uint4*)((char*)sA + r * 640 + (((256 + c0) * 2) ^ swz)) = xv;
    }

    __syncthreads();

    // ---- edge aggregation: scalar meta (s_load), ping-pong gathers ----
    const int sbase = wid * 32;
    int E0 = __builtin_amdgcn_readfirstlane(sRP[sbase]);
    int E1 = __builtin_amdgcn_readfirstlane(sRP[sbase + 32]);
    int seg = 0;
    int segEnd = __builtin_amdgcn_readfirstlane(sRP[sbase + 1]);
    float acc = 0.f, dsum = 0.f;

    unsigned short ga[16], gb[16];
    gather16<0>(ga, edat + E0, xb, lane);

    int e = E0;
    for (; e + 32 <= E1; e += 32) {
        gather16<16>(gb, edat + e, xb, lane);
        consume16<0, false>(ga, edat + e, e, E1, seg, segEnd, acc, dsum,
                            sRP, sbase, wid, lane, (char*)sA);
        gather16<0>(ga, edat + e + 32, xb, lane);
        consume16<16, false>(gb, edat + e, e + 16, E1, seg, segEnd, acc, dsum,
                             sRP, sbase, wid, lane, (char*)sA);
    }
    if (e < E1) {                    // guarded tail (<32 edges)
        gather16<16>(gb, edat + e, xb, lane);
        consume16<0, true>(ga, edat + e, e, E1, seg, segEnd, acc, dsum,
                           sRP, sbase, wid, lane, (char*)sA);
        consume16<16, true>(gb, edat + e, e + 16, E1, seg, segEnd, acc, dsum,
                            sRP, sbase, wid, lane, (char*)sA);
    }

    while (seg < 32) {               // trailing flush
        float u = acc * __builtin_amdgcn_rcpf(dsum + EPS);
        int ln = wid * 8 + (seg >> 2);
        int cb = ((seg & 3) * 64 + lane) * 2;
        *(unsigned short*)((char*)sA + ln * 640 + (cb ^ ((ln & 7) << 4))) = f2bf(u);
        acc = 0.f; dsum = 0.f;
        ++seg;
    }

    bfrag8 bwL[10];
    #pragma unroll
    for (int ks = 0; ks < 10; ++ks)
        bwL[ks] = *(const bfrag8*)((const char*)WL + bcol * 640 + ks * 64 + koff2);
    float biasC = lin_b[bcol] + self_b[bcol];
    float pbv = pb[bcol], tbv = tb[bcol];

    __syncthreads();

    // ---- conv MFMA: 2 row-tiles × K=320 ----
    f4acc accC0 = {0.f, 0.f, 0.f, 0.f};
    f4acc accC1 = {0.f, 0.f, 0.f, 0.f};
    #pragma unroll
    for (int ks = 0; ks < 10; ++ks) {
        int co = ks * 64 + koff2;
        bfrag8 a0 = *(const bfrag8*)((const char*)sA + arow * 640 +
                                     (co ^ ((arow & 7) << 4)));
        bfrag8 a1 = *(const bfrag8*)((const char*)sA + (16 + arow) * 640 +
                                     (co ^ (((16 + arow) & 7) << 4)));
        accC0 = __builtin_amdgcn_mfma_f32_16x16x32_bf16(a0, bwL[ks], accC0, 0, 0, 0);
        accC1 = __builtin_amdgcn_mfma_f32_16x16x32_bf16(a1, bwL[ks], accC1, 0, 0, 0);
    }

    bfrag8 bwP[4], bwT[4];
    #pragma unroll
    for (int ks = 0; ks < 4; ++ks) {
        bwP[ks] = *(const bfrag8*)((const char*)WP  + bcol * 256 + ks * 64 + koff2);
        bwT[ks] = *(const bfrag8*)((const char*)WT2 + bcol * 256 + ks * 64 + koff2);
    }

    // sigmoid; stage hid into sH cols 0..63; store hidden bf16
    float hid[8];
    #pragma unroll
    for (int rt = 0; rt < 2; ++rt) {
        #pragma unroll
        for (int q = 0; q < 4; ++q) {
            float o = (rt == 0 ? accC0[q] : accC1[q]) + biasC;
            float h = 1.f / (1.f + __expf(-o));
            hid[rt * 4 + q] = h;
            int row = rt * 16 + hi * 4 + q;
            unsigned short hb = f2bf(h);
            *(unsigned short*)((char*)sH + row * 256 +
                               ((bcol * 2) ^ ((row & 7) << 4))) = hb;
            hidb[(size_t)(n0 + row) * 64 + bcol] = hb;
        }
    }

    __syncthreads();

    // ---- highway MFMA: cat=[hid, prev], K=128, 2 row-tiles ----
    f4acc accP0 = {0.f, 0.f, 0.f, 0.f};
    f4acc accP1 = {0.f, 0.f, 0.f, 0.f};
    f4acc accT0 = {0.f, 0.f, 0.f, 0.f};
    f4acc accT1 = {0.f, 0.f, 0.f, 0.f};
    #pragma unroll
    for (int ks = 0; ks < 4; ++ks) {
        int co = ks * 64 + koff2;
        bfrag8 a0 = *(const bfrag8*)((const char*)sH + arow * 256 +
                                     (co ^ ((arow & 7) << 4)));
        bfrag8 a1 = *(const bfrag8*)((const char*)sH + (16 + arow) * 256 +
                                     (co ^ (((16 + arow) & 7) << 4)));
        accP0 = __builtin_amdgcn_mfma_f32_16x16x32_bf16(a0, bwP[ks], accP0, 0, 0, 0);
        accP1 = __builtin_amdgcn_mfma_f32_16x16x32_bf16(a1, bwP[ks], accP1, 0, 0, 0);
        accT0 = __builtin_amdgcn_mfma_f32_16x16x32_bf16(a0, bwT[ks], accT0, 0, 0, 0);
        accT1 = __builtin_amdgcn_mfma_f32_16x16x32_bf16(a1, bwT[ks], accT1, 0, 0, 0);
    }

    #pragma unroll
    for (int rt = 0; rt < 2; ++rt) {
        #pragma unroll
        for (int q = 0; q < 4; ++q) {
            float ap = (rt == 0 ? accP0[q] : accP1[q]);
            float at = (rt == 0 ? accT0[q] : accT1[q]);
            float proj = fmaxf(ap + pbv, 0.f);
            float gate = 1.f / (1.f + __expf(-(at + tbv)));
            float o = gate * proj + (1.f - gate) * hid[rt * 4 + q];
            int row = rt * 16 + hi * 4 + q;
            if (last) outf[(size_t)(n0 + row) * 64 + bcol] = o;
            else      gatedb[(size_t)(n0 + row) * 64 + bcol] = f2bf(o);
        }
    }
}

// ---------------------------------------------------------------------------
extern "C" void kernel_launch(void* const* d_in, const int* in_sizes, int n_in,
                              void* d_out, int out_size, void* d_ws, size_t ws_size,
                              hipStream_t stream)
{
    const float* node_feat = (const float*)d_in[0];
    const float* ew        = (const float*)d_in[1];
    const float* lin_w     = (const float*)d_in[2];
    const float* lin_b     = (const float*)d_in[3];
    const float* self_w    = (const float*)d_in[4];
    const float* self_b    = (const float*)d_in[5];
    const float* pw        = (const float*)d_in[6];
    const float* pb        = (const float*)d_in[7];
    const float* tw        = (const float*)d_in[8];
    const float* tb        = (const float*)d_in[9];
    const int*   src       = (const int*)d_in[10];
    const int*   dst       = (const int*)d_in[11];
    const int*   rel       = (const int*)d_in[12];
    float* outf = (float*)d_out;

    char* ws = (char*)d_ws;
    // fused-scan buffers: scanout[0..NB] = row_ptr (incl total at NB),
    // scanout+NB = chunkOff (biased by +NE, subtracted in kA3)
    int*            scanout  = (int*)(ws + 0);            // NSCAN*4 = 2000384
    int*            cnt_cat  = (int*)(ws + 2000640);      // NSCAN*4
    int*            blksum   = (int*)(ws + 4001280);      // 512*4
    int*            blkoff   = (int*)(ws + 4003328);      // 512*4
    int2*           pA       = (int2*)(ws + 4005888);     // NE*8
    int2*           edat     = (int2*)(ws + 16805888);    // (NE+192)*8
    unsigned short* nfb      = (unsigned short*)(ws + 29607424);
    unsigned short* hbfA     = (unsigned short*)(ws + 42407424);
    unsigned short* hbfB     = (unsigned short*)(ws + 55207424);
    unsigned short* gbfA     = (unsigned short*)(ws + 68007424);
    unsigned short* gbfB     = (unsigned short*)(ws + 80807424);
    unsigned short* WL       = (unsigned short*)(ws + 93607424);
    unsigned short* WP       = (unsigned short*)(ws + 93607424 + 122880);
    unsigned short* WT2      = (unsigned short*)(ws + 93607424 + 122880 + 49152);

    int* row_ptr  = scanout;
    int* chunkOff = scanout + NB;
    int* cnt_seg  = cnt_cat;
    int* histBC   = cnt_cat + NB;

    // ---- CSR build: deterministic two-phase counting sort, fused scan ----
    hipMemsetAsync(cnt_cat, 0, NSCAN * sizeof(int), stream);
    kA1<<<NCHK, 256, 0, stream>>>(dst, rel, cnt_seg, histBC);
    k_scan_local_g<<<NBLK_FUSED, 1024, 0, stream>>>(cnt_cat, scanout, blksum, NSCAN);
    k_scan_blk_g<<<1, 512, 0, stream>>>(blksum, blkoff, NBLK_FUSED);
    k_scan_add_g<<<NBLK_FUSED, 1024, 0, stream>>>(scanout, blkoff, NSCAN);
    kA3<<<NCHK, 256, 0, stream>>>(src, dst, rel, ew, chunkOff, pA);
    kB<<<NBUCK, 256, 0, stream>>>(row_ptr, pA, edat);

    // bf16 conversions
    k_cvt_x<<<25000, 256, 0, stream>>>(node_feat, nfb);
    k_cvt_w<<<432, 256, 0, stream>>>(lin_w, self_w, pw, tw, WL, WP, WT2);

    const unsigned short* cur  = nfb;
    const unsigned short* prev = nfb;
    unsigned short* hbuf[3] = { hbfA, hbfB, hbfA };
    unsigned short* gbuf[3] = { gbfA, gbfB, gbfA };

    for (int i = 0; i < 3; ++i) {
        int lastL = (i == 2);
        k_layer<<<NN / NPB, 256, 0, stream>>>(
            cur, prev, row_ptr, edat,
            WL  + (size_t)i * 64 * 320,
            WP  + (size_t)i * 64 * 128,
            WT2 + (size_t)i * 64 * 128,
            lin_b + (size_t)i * 64, self_b + (size_t)i * 64,
            pb + (size_t)i * 64, tb + (size_t)i * 64,
            hbuf[i], gbuf[i], outf, lastL);
        cur  = gbuf[i];
        prev = hbuf[i];
    }
}

// Round 13
// 330.038 us; speedup vs baseline: 1.1192x; 1.1192x over previous
//
#include <hip/hip_runtime.h>

#define NN   100000
#define NE   1600000
#define NB   400000     // NN*4 (dst,rel) segments
#define EPS  1e-10f

#define NPB   32        // nodes per block
#define NCHK  256       // edge chunks (phase A blocks)
#define EPC   6250      // NE / NCHK
#define NBUCK 391       // coarse buckets: dst>>8  (ceil(100000/256))
#define NHBC  (NBUCK * NCHK)   // 100096
#define NSCAN (NB + NHBC)      // 500096 fused scan length
#define NBLK_FUSED 489         // ceil(NSCAN/1024)

typedef __attribute__((ext_vector_type(8))) short bfrag8;
typedef __attribute__((ext_vector_type(4))) float f4acc;

__device__ __forceinline__ unsigned short f2bf(float f) {
    union { float f; unsigned u; } v; v.f = f;
    unsigned r = v.u + 0x7FFF + ((v.u >> 16) & 1);
    return (unsigned short)(r >> 16);
}
__device__ __forceinline__ float bf2f(unsigned short b) {
    union { unsigned u; float f; } v; v.u = ((unsigned)b) << 16;
    return v.f;
}

// ---------------------------------------------------------------------------
// Phase A1: per-(bucket,chunk) histogram in LDS  +  400K segment histogram
// ---------------------------------------------------------------------------
__global__ __launch_bounds__(256) void kA1(
    const int* __restrict__ dst, const int* __restrict__ rel,
    int* __restrict__ cnt_seg, int* __restrict__ histBC)
{
    __shared__ int s_h[NBUCK];
    for (int i = threadIdx.x; i < NBUCK; i += 256) s_h[i] = 0;
    __syncthreads();
    int e0 = blockIdx.x * EPC;
    for (int e = e0 + threadIdx.x; e < e0 + EPC; e += 256) {
        int d = dst[e];
        atomicAdd(&s_h[d >> 8], 1);
        atomicAdd(&cnt_seg[d * 4 + rel[e]], 1);
    }
    __syncthreads();
    for (int i = threadIdx.x; i < NBUCK; i += 256)
        histBC[i * NCHK + blockIdx.x] = s_h[i];   // bucket-major
}

// --- generic coalesced 3-phase scan ----------------------------------------
__global__ __launch_bounds__(1024) void k_scan_local_g(
    const int* __restrict__ in, int* __restrict__ out,
    int* __restrict__ blksum, int n)
{
    __shared__ int s[1024];
    int t = threadIdx.x;
    int i = blockIdx.x * 1024 + t;
    int v = (i < n) ? in[i] : 0;
    s[t] = v;
    __syncthreads();
    #pragma unroll
    for (int off = 1; off < 1024; off <<= 1) {
        int u = (t >= off) ? s[t - off] : 0;
        __syncthreads();
        s[t] += u;
        __syncthreads();
    }
    if (i < n) out[i] = s[t] - v;
    if (t == 1023) blksum[blockIdx.x] = s[t];
}

__global__ __launch_bounds__(512) void k_scan_blk_g(
    int* __restrict__ blksum, int* __restrict__ blkoff, int nblk)
{
    __shared__ int s[512];
    int t = threadIdx.x;
    int v = (t < nblk) ? blksum[t] : 0;
    s[t] = v;
    __syncthreads();
    #pragma unroll
    for (int off = 1; off < 512; off <<= 1) {
        int u = (t >= off) ? s[t - off] : 0;
        __syncthreads();
        s[t] += u;
        __syncthreads();
    }
    if (t < nblk) blkoff[t] = s[t] - v;
}

__global__ __launch_bounds__(1024) void k_scan_add_g(
    int* __restrict__ out, const int* __restrict__ blkoff, int n)
{
    int i = blockIdx.x * 1024 + threadIdx.x;
    if (i < n) out[i] += blkoff[blockIdx.x];
}

// ---------------------------------------------------------------------------
// Phase A3: partition edges into coarse buckets (line-dense writes).
// chunkOff entries carry a +NE bias from the fused scan; subtract here.
// ---------------------------------------------------------------------------
__global__ __launch_bounds__(256) void kA3(
    const int* __restrict__ src, const int* __restrict__ dst,
    const int* __restrict__ rel, const float* __restrict__ ew,
    const int* __restrict__ chunkOff, int2* __restrict__ pA)
{
    __shared__ int s_c[NBUCK];
    for (int i = threadIdx.x; i < NBUCK; i += 256)
        s_c[i] = chunkOff[i * NCHK + blockIdx.x] - NE;
    __syncthreads();
    int e0 = blockIdx.x * EPC;
    for (int e = e0 + threadIdx.x; e < e0 + EPC; e += 256) {
        int d = dst[e], r = rel[e];
        int pos = atomicAdd(&s_c[d >> 8], 1);
        int2 v;
        v.x = src[e] | (((d & 255) * 4 + r) << 20);
        v.y = __float_as_int(ew[e]);
        pA[pos] = v;
    }
}

// ---------------------------------------------------------------------------
// Phase B: one block per bucket; in-bucket counting sort by seg_local.
// ---------------------------------------------------------------------------
__global__ __launch_bounds__(256) void kB(
    const int* __restrict__ row_ptr, const int2* __restrict__ pA,
    int2* __restrict__ edat)
{
    __shared__ int s_c[1024];
    __shared__ int s_p[256];
    const int b    = blockIdx.x;
    const int t    = threadIdx.x;
    const int seg0 = b * 1024;
    const int segN = min(1024, NB - seg0);
    const int pbeg = row_ptr[seg0];
    const int pend = row_ptr[seg0 + segN];

    for (int i = t; i < 1024; i += 256) s_c[i] = 0;
    __syncthreads();
    for (int p = pbeg + t; p < pend; p += 256)
        atomicAdd(&s_c[((unsigned)pA[p].x) >> 20], 1);
    __syncthreads();

    int c0 = s_c[t * 4], c1 = s_c[t * 4 + 1], c2 = s_c[t * 4 + 2], c3 = s_c[t * 4 + 3];
    int tsum = c0 + c1 + c2 + c3;
    s_p[t] = tsum;
    __syncthreads();
    #pragma unroll
    for (int off = 1; off < 256; off <<= 1) {
        int u = (t >= off) ? s_p[t - off] : 0;
        __syncthreads();
        s_p[t] += u;
        __syncthreads();
    }
    int base = s_p[t] - tsum;
    s_c[t * 4]     = base;
    s_c[t * 4 + 1] = base + c0;
    s_c[t * 4 + 2] = base + c0 + c1;
    s_c[t * 4 + 3] = base + c0 + c1 + c2;
    __syncthreads();

    for (int p = pbeg + t; p < pend; p += 256) {
        int2 v = pA[p];
        int sl = ((unsigned)v.x) >> 20;
        int pos = atomicAdd(&s_c[sl], 1);
        int2 o; o.x = v.x & 0xFFFFF; o.y = v.y;
        edat[pbeg + pos] = o;
    }
    // 192 zero pad entries: layer kernel over-reads meta up to NE+~160
    if (b == 0 && t < 192) { int2 z; z.x = 0; z.y = 0; edat[NE + t] = z; }
}

// ---------------------------------------------------------------------------
// Conversions
// ---------------------------------------------------------------------------
__global__ __launch_bounds__(256) void k_cvt_x(
    const float* __restrict__ xf, unsigned short* __restrict__ xb)
{
    int i = blockIdx.x * 256 + threadIdx.x;
    if (i < NN * 64) xb[i] = f2bf(xf[i]);
}

__global__ __launch_bounds__(256) void k_cvt_w(
    const float* __restrict__ lin_w, const float* __restrict__ self_w,
    const float* __restrict__ pw, const float* __restrict__ tw,
    unsigned short* __restrict__ WL, unsigned short* __restrict__ WP,
    unsigned short* __restrict__ WT2)
{
    int id = blockIdx.x * 256 + threadIdx.x;   // 3*64*576
    if (id >= 3 * 64 * 576) return;
    int i = id / (64 * 576);
    int r = id % (64 * 576);
    int j = r / 576;
    int k = r % 576;
    if (k < 320) {
        float v = (k < 256) ? lin_w[((size_t)i * 256 + k) * 64 + j]
                            : self_w[((size_t)i * 64 + (k - 256)) * 64 + j];
        WL[((size_t)i * 64 + j) * 320 + k] = f2bf(v);
    } else if (k < 448) {
        int kk = k - 320;
        WP[((size_t)i * 64 + j) * 128 + kk] = f2bf(pw[((size_t)i * 128 + kk) * 64 + j]);
    } else {
        int kk = k - 448;
        WT2[((size_t)i * 64 + j) * 128 + kk] = f2bf(tw[((size_t)i * 128 + kk) * 64 + j]);
    }
}

// ---------------------------------------------------------------------------
// Scalarized edge-stream helpers for k_layer (R11-proven readlane meta path).
// ---------------------------------------------------------------------------
template<int LBASE>
__device__ __forceinline__ void gather16(
    unsigned short (&g)[16], int2 mb,
    const unsigned short* __restrict__ xb, int lane)
{
    #pragma unroll
    for (int j = 0; j < 16; ++j) {
        unsigned sm = (unsigned)__builtin_amdgcn_readlane(mb.x, LBASE + j);
        g[j] = xb[((size_t)sm << 6) + lane];
    }
}

template<int LBASE, bool CHECK>
__device__ __forceinline__ void consume16(
    const unsigned short (&g)[16], int2 mb, int ebase,
    int E1, int& seg, int& segEnd,
    float& acc, float& dsum,
    const int* sRP, int sbase, int wid, int lane, char* sAp)
{
    #pragma unroll
    for (int j = 0; j < 16; ++j) {
        int eidx = ebase + j;                          // scalar
        if (!CHECK || eidx < E1) {                     // s_cmp path (tail only)
            while (eidx >= segEnd) {                   // flush finished segments
                float u = acc * __builtin_amdgcn_rcpf(dsum + EPS);
                int ln = wid * 8 + (seg >> 2);
                int cb = ((seg & 3) * 64 + lane) * 2;
                *(unsigned short*)(sAp + ln * 640 + (cb ^ ((ln & 7) << 4))) = f2bf(u);
                acc = 0.f; dsum = 0.f;
                ++seg;
                segEnd = __builtin_amdgcn_readfirstlane(sRP[sbase + seg + 1]);
            }
            float w = __int_as_float(__builtin_amdgcn_readlane(mb.y, LBASE + j));
            acc = fmaf(bf2f(g[j]), w, acc);
            dsum += w;
        }
    }
}

template<bool CHECK>
__device__ __forceinline__ void agg_iter64(
    unsigned short (&ga)[16], unsigned short (&gb)[16],
    int2& mb, int e, int E1, int& seg, int& segEnd,
    float& acc, float& dsum, const int* sRP, int sbase,
    int wid, int lane, char* sAp,
    const unsigned short* __restrict__ xb, const int2* __restrict__ edat)
{
    int2 mbn = edat[e + 64 + lane];              // next meta block (padded)
    gather16<16>(gb, mb, xb, lane);
    consume16<0, CHECK>(ga, mb, e, E1, seg, segEnd, acc, dsum, sRP, sbase, wid, lane, sAp);
    gather16<32>(ga, mb, xb, lane);
    consume16<16, CHECK>(gb, mb, e + 16, E1, seg, segEnd, acc, dsum, sRP, sbase, wid, lane, sAp);
    gather16<48>(gb, mb, xb, lane);
    consume16<32, CHECK>(ga, mb, e + 32, E1, seg, segEnd, acc, dsum, sRP, sbase, wid, lane, sAp);
    gather16<0>(ga, mbn, xb, lane);
    consume16<48, CHECK>(gb, mb, e + 48, E1, seg, segEnd, acc, dsum, sRP, sbase, wid, lane, sAp);
    mb = mbn;
}

// ---------------------------------------------------------------------------
// Fused layer: 32 nodes/block, 4 waves; wave aggregates 8 nodes (32 segs),
// then computes its 16-col tile over 2 row-tiles in the MFMA phases.
// Single change vs R11: __launch_bounds__(256,5) -> 5 blocks/CU (LDS-limited).
// ---------------------------------------------------------------------------
__global__ __launch_bounds__(256, 5) void k_layer(
    const unsigned short* __restrict__ xb,     // layer input bf16 [NN][64]
    const unsigned short* __restrict__ prevb,  // prev hidden bf16 [NN][64]
    const int* __restrict__ row_ptr,
    const int2* __restrict__ edat,
    const unsigned short* __restrict__ WL,     // [64][320]
    const unsigned short* __restrict__ WP,     // [64][128]
    const unsigned short* __restrict__ WT2,    // [64][128]
    const float* __restrict__ lin_b, const float* __restrict__ self_b,
    const float* __restrict__ pb, const float* __restrict__ tb,
    unsigned short* __restrict__ hidb,
    unsigned short* __restrict__ gatedb,
    float* __restrict__ outf,
    int last)
{
    __shared__ __align__(16) unsigned short sA[NPB * 320];  // 20480 B
    __shared__ __align__(16) unsigned short sH[NPB * 128];  //  8192 B
    __shared__ int sRP[NPB * 4 + 1];                        // 129 entries

    const int tid  = threadIdx.x;
    const int lane = tid & 63;
    const int wid  = tid >> 6;
    const int n0   = blockIdx.x * NPB;
    const int bcol = wid * 16 + (lane & 15);
    const int koff2 = (lane >> 4) * 16;
    const int arow = lane & 15;
    const int hi   = lane >> 4;

    if (tid < NPB * 4 + 1) sRP[tid] = row_ptr[n0 * 4 + tid];

    // ---- vectorized staging: 16 B per thread per tile ----
    {
        int r  = tid >> 3;            // 0..31
        int c0 = (tid & 7) * 8;       // 0,8,...,56
        uint4 pv = *(const uint4*)&prevb[(size_t)(n0 + r) * 64 + c0];
        int swz = (r & 7) << 4;
        *(uint4*)((char*)sH + r * 256 + (((64 + c0) * 2) ^ swz)) = pv;
        uint4 xv = *(const uint4*)&xb[(size_t)(n0 + r) * 64 + c0];
        *(uint4*)((char*)sA + r * 640 + (((256 + c0) * 2) ^ swz)) = xv;
    }

    __syncthreads();

    // ---- scalarized edge aggregation (ping-pong, ~16-32 in flight) ----
    const int sbase = wid * 32;
    int E0 = __builtin_amdgcn_readfirstlane(sRP[sbase]);
    int E1 = __builtin_amdgcn_readfirstlane(sRP[sbase + 32]);
    int seg = 0;
    int segEnd = __builtin_amdgcn_readfirstlane(sRP[sbase + 1]);
    float acc = 0.f, dsum = 0.f;

    int2 mb = edat[E0 + lane];       // meta for edges E0..E0+63 (lane j = edge j)
    unsigned short ga[16], gb[16];
    gather16<0>(ga, mb, xb, lane);

    int e = E0;
    for (; e + 64 <= E1; e += 64)    // full blocks: no per-edge E1 guard
        agg_iter64<false>(ga, gb, mb, e, E1, seg, segEnd, acc, dsum,
                          sRP, sbase, wid, lane, (char*)sA, xb, edat);
    if (e < E1)                      // guarded tail
        agg_iter64<true>(ga, gb, mb, e, E1, seg, segEnd, acc, dsum,
                         sRP, sbase, wid, lane, (char*)sA, xb, edat);

    while (seg < 32) {               // trailing flush
        float u = acc * __builtin_amdgcn_rcpf(dsum + EPS);
        int ln = wid * 8 + (seg >> 2);
        int cb = ((seg & 3) * 64 + lane) * 2;
        *(unsigned short*)((char*)sA + ln * 640 + (cb ^ ((ln & 7) << 4))) = f2bf(u);
        acc = 0.f; dsum = 0.f;
        ++seg;
    }

    bfrag8 bwL[10];
    #pragma unroll
    for (int ks = 0; ks < 10; ++ks)
        bwL[ks] = *(const bfrag8*)((const char*)WL + bcol * 640 + ks * 64 + koff2);
    float biasC = lin_b[bcol] + self_b[bcol];
    float pbv = pb[bcol], tbv = tb[bcol];

    __syncthreads();

    // ---- conv MFMA: 2 row-tiles × K=320 ----
    f4acc accC0 = {0.f, 0.f, 0.f, 0.f};
    f4acc accC1 = {0.f, 0.f, 0.f, 0.f};
    #pragma unroll
    for (int ks = 0; ks < 10; ++ks) {
        int co = ks * 64 + koff2;
        bfrag8 a0 = *(const bfrag8*)((const char*)sA + arow * 640 +
                                     (co ^ ((arow & 7) << 4)));
        bfrag8 a1 = *(const bfrag8*)((const char*)sA + (16 + arow) * 640 +
                                     (co ^ (((16 + arow) & 7) << 4)));
        accC0 = __builtin_amdgcn_mfma_f32_16x16x32_bf16(a0, bwL[ks], accC0, 0, 0, 0);
        accC1 = __builtin_amdgcn_mfma_f32_16x16x32_bf16(a1, bwL[ks], accC1, 0, 0, 0);
    }

    bfrag8 bwP[4], bwT[4];
    #pragma unroll
    for (int ks = 0; ks < 4; ++ks) {
        bwP[ks] = *(const bfrag8*)((const char*)WP  + bcol * 256 + ks * 64 + koff2);
        bwT[ks] = *(const bfrag8*)((const char*)WT2 + bcol * 256 + ks * 64 + koff2);
    }

    // sigmoid; stage hid into sH cols 0..63; store hidden bf16
    float hid[8];
    #pragma unroll
    for (int rt = 0; rt < 2; ++rt) {
        #pragma unroll
        for (int q = 0; q < 4; ++q) {
            float o = (rt == 0 ? accC0[q] : accC1[q]) + biasC;
            float h = 1.f / (1.f + __expf(-o));
            hid[rt * 4 + q] = h;
            int row = rt * 16 + hi * 4 + q;
            unsigned short hb = f2bf(h);
            *(unsigned short*)((char*)sH + row * 256 +
                               ((bcol * 2) ^ ((row & 7) << 4))) = hb;
            hidb[(size_t)(n0 + row) * 64 + bcol] = hb;
        }
    }

    __syncthreads();

    // ---- highway MFMA: cat=[hid, prev], K=128, 2 row-tiles ----
    f4acc accP0 = {0.f, 0.f, 0.f, 0.f};
    f4acc accP1 = {0.f, 0.f, 0.f, 0.f};
    f4acc accT0 = {0.f, 0.f, 0.f, 0.f};
    f4acc accT1 = {0.f, 0.f, 0.f, 0.f};
    #pragma unroll
    for (int ks = 0; ks < 4; ++ks) {
        int co = ks * 64 + koff2;
        bfrag8 a0 = *(const bfrag8*)((const char*)sH + arow * 256 +
                                     (co ^ ((arow & 7) << 4)));
        bfrag8 a1 = *(const bfrag8*)((const char*)sH + (16 + arow) * 256 +
                                     (co ^ (((16 + arow) & 7) << 4)));
        accP0 = __builtin_amdgcn_mfma_f32_16x16x32_bf16(a0, bwP[ks], accP0, 0, 0, 0);
        accP1 = __builtin_amdgcn_mfma_f32_16x16x32_bf16(a1, bwP[ks], accP1, 0, 0, 0);
        accT0 = __builtin_amdgcn_mfma_f32_16x16x32_bf16(a0, bwT[ks], accT0, 0, 0, 0);
        accT1 = __builtin_amdgcn_mfma_f32_16x16x32_bf16(a1, bwT[ks], accT1, 0, 0, 0);
    }

    #pragma unroll
    for (int rt = 0; rt < 2; ++rt) {
        #pragma unroll
        for (int q = 0; q < 4; ++q) {
            float ap = (rt == 0 ? accP0[q] : accP1[q]);
            float at = (rt == 0 ? accT0[q] : accT1[q]);
            float proj = fmaxf(ap + pbv, 0.f);
            float gate = 1.f / (1.f + __expf(-(at + tbv)));
            float o = gate * proj + (1.f - gate) * hid[rt * 4 + q];
            int row = rt * 16 + hi * 4 + q;
            if (last) outf[(size_t)(n0 + row) * 64 + bcol] = o;
            else      gatedb[(size_t)(n0 + row) * 64 + bcol] = f2bf(o);
        }
    }
}

// ---------------------------------------------------------------------------
extern "C" void kernel_launch(void* const* d_in, const int* in_sizes, int n_in,
                              void* d_out, int out_size, void* d_ws, size_t ws_size,
                              hipStream_t stream)
{
    const float* node_feat = (const float*)d_in[0];
    const float* ew        = (const float*)d_in[1];
    const float* lin_w     = (const float*)d_in[2];
    const float* lin_b     = (const float*)d_in[3];
    const float* self_w    = (const float*)d_in[4];
    const float* self_b    = (const float*)d_in[5];
    const float* pw        = (const float*)d_in[6];
    const float* pb        = (const float*)d_in[7];
    const float* tw        = (const float*)d_in[8];
    const float* tb        = (const float*)d_in[9];
    const int*   src       = (const int*)d_in[10];
    const int*   dst       = (const int*)d_in[11];
    const int*   rel       = (const int*)d_in[12];
    float* outf = (float*)d_out;

    char* ws = (char*)d_ws;
    // fused-scan buffers: scanout[0..NB] = row_ptr (incl total at NB),
    // scanout+NB = chunkOff (biased by +NE, subtracted in kA3)
    int*            scanout  = (int*)(ws + 0);            // NSCAN*4 = 2000384
    int*            cnt_cat  = (int*)(ws + 2000640);      // NSCAN*4
    int*            blksum   = (int*)(ws + 4001280);      // 512*4
    int*            blkoff   = (int*)(ws + 4003328);      // 512*4
    int2*           pA       = (int2*)(ws + 4005888);     // NE*8
    int2*           edat     = (int2*)(ws + 16805888);    // (NE+192)*8
    unsigned short* nfb      = (unsigned short*)(ws + 29607424);
    unsigned short* hbfA     = (unsigned short*)(ws + 42407424);
    unsigned short* hbfB     = (unsigned short*)(ws + 55207424);
    unsigned short* gbfA     = (unsigned short*)(ws + 68007424);
    unsigned short* gbfB     = (unsigned short*)(ws + 80807424);
    unsigned short* WL       = (unsigned short*)(ws + 93607424);
    unsigned short* WP       = (unsigned short*)(ws + 93607424 + 122880);
    unsigned short* WT2      = (unsigned short*)(ws + 93607424 + 122880 + 49152);

    int* row_ptr  = scanout;
    int* chunkOff = scanout + NB;
    int* cnt_seg  = cnt_cat;
    int* histBC   = cnt_cat + NB;

    // ---- CSR build: deterministic two-phase counting sort, fused scan ----
    hipMemsetAsync(cnt_cat, 0, NSCAN * sizeof(int), stream);
    kA1<<<NCHK, 256, 0, stream>>>(dst, rel, cnt_seg, histBC);
    k_scan_local_g<<<NBLK_FUSED, 1024, 0, stream>>>(cnt_cat, scanout, blksum, NSCAN);
    k_scan_blk_g<<<1, 512, 0, stream>>>(blksum, blkoff, NBLK_FUSED);
    k_scan_add_g<<<NBLK_FUSED, 1024, 0, stream>>>(scanout, blkoff, NSCAN);
    kA3<<<NCHK, 256, 0, stream>>>(src, dst, rel, ew, chunkOff, pA);
    kB<<<NBUCK, 256, 0, stream>>>(row_ptr, pA, edat);

    // bf16 conversions
    k_cvt_x<<<25000, 256, 0, stream>>>(node_feat, nfb);
    k_cvt_w<<<432, 256, 0, stream>>>(lin_w, self_w, pw, tw, WL, WP, WT2);

    const unsigned short* cur  = nfb;
    const unsigned short* prev = nfb;
    unsigned short* hbuf[3] = { hbfA, hbfB, hbfA };
    unsigned short* gbuf[3] = { gbfA, gbfB, gbfA };

    for (int i = 0; i < 3; ++i) {
        int lastL = (i == 2);
        k_layer<<<NN / NPB, 256, 0, stream>>>(
            cur, prev, row_ptr, edat,
            WL  + (size_t)i * 64 * 320,
            WP  + (size_t)i * 64 * 128,
            WT2 + (size_t)i * 64 * 128,
            lin_b + (size_t)i * 64, self_b + (size_t)i * 64,
            pb + (size_t)i * 64, tb + (size_t)i * 64,
            hbuf[i], gbuf[i], outf, lastL);
        cur  = gbuf[i];
        prev = hbuf[i];
    }
}

// Round 14
// 325.427 us; speedup vs baseline: 1.1351x; 1.0142x over previous
//
#include <hip/hip_runtime.h>

#define NN   100000
#define NE   1600000
#define NB   400000     // NN*4 (dst,rel) segments
#define EPS  1e-10f

#define NPB   32        // nodes per block
#define NCHK  256       // edge chunks (phase A blocks)
#define EPC   6250      // NE / NCHK
#define NBUCK 391       // coarse buckets: dst>>8  (ceil(100000/256))
#define NHBC  (NBUCK * NCHK)   // 100096
#define NSCAN (NB + NHBC)      // 500096 fused scan length
#define NBLK_FUSED 489         // ceil(NSCAN/1024)
#define KB_CAP 4608            // kB LDS edge cache (avg bucket 4091, +8 sigma)

typedef __attribute__((ext_vector_type(8))) short bfrag8;
typedef __attribute__((ext_vector_type(4))) float f4acc;

__device__ __forceinline__ unsigned short f2bf(float f) {
    union { float f; unsigned u; } v; v.f = f;
    unsigned r = v.u + 0x7FFF + ((v.u >> 16) & 1);
    return (unsigned short)(r >> 16);
}
__device__ __forceinline__ float bf2f(unsigned short b) {
    union { unsigned u; float f; } v; v.u = ((unsigned)b) << 16;
    return v.f;
}

// ---------------------------------------------------------------------------
// Phase A1: per-(bucket,chunk) histogram + 400K segment histogram
//           + (fused, independent) node-feature f32 -> bf16 conversion
// ---------------------------------------------------------------------------
__global__ __launch_bounds__(256) void kA1(
    const int* __restrict__ dst, const int* __restrict__ rel,
    int* __restrict__ cnt_seg, int* __restrict__ histBC,
    const float* __restrict__ xf, unsigned short* __restrict__ xb)
{
    __shared__ int s_h[NBUCK];
    for (int i = threadIdx.x; i < NBUCK; i += 256) s_h[i] = 0;
    __syncthreads();
    int e0 = blockIdx.x * EPC;
    for (int e = e0 + threadIdx.x; e < e0 + EPC; e += 256) {
        int d = dst[e];
        atomicAdd(&s_h[d >> 8], 1);
        atomicAdd(&cnt_seg[d * 4 + rel[e]], 1);
    }
    __syncthreads();
    for (int i = threadIdx.x; i < NBUCK; i += 256)
        histBC[i * NCHK + blockIdx.x] = s_h[i];   // bucket-major

    // fused cvt_x: 8 elems per iteration per thread (independent of above)
    for (int c = blockIdx.x * 256 + threadIdx.x; c < NN * 8; c += NCHK * 256) {
        const float4* s4 = (const float4*)xf + (size_t)c * 2;
        float4 a = s4[0], b = s4[1];
        unsigned short r[8] = { f2bf(a.x), f2bf(a.y), f2bf(a.z), f2bf(a.w),
                                f2bf(b.x), f2bf(b.y), f2bf(b.z), f2bf(b.w) };
        *(uint4*)(xb + (size_t)c * 8) = *(const uint4*)r;
    }
}

// --- generic coalesced 3-phase scan ----------------------------------------
__global__ __launch_bounds__(1024) void k_scan_local_g(
    const int* __restrict__ in, int* __restrict__ out,
    int* __restrict__ blksum, int n)
{
    __shared__ int s[1024];
    int t = threadIdx.x;
    int i = blockIdx.x * 1024 + t;
    int v = (i < n) ? in[i] : 0;
    s[t] = v;
    __syncthreads();
    #pragma unroll
    for (int off = 1; off < 1024; off <<= 1) {
        int u = (t >= off) ? s[t - off] : 0;
        __syncthreads();
        s[t] += u;
        __syncthreads();
    }
    if (i < n) out[i] = s[t] - v;
    if (t == 1023) blksum[blockIdx.x] = s[t];
}

__global__ __launch_bounds__(512) void k_scan_blk_g(
    int* __restrict__ blksum, int* __restrict__ blkoff, int nblk)
{
    __shared__ int s[512];
    int t = threadIdx.x;
    int v = (t < nblk) ? blksum[t] : 0;
    s[t] = v;
    __syncthreads();
    #pragma unroll
    for (int off = 1; off < 512; off <<= 1) {
        int u = (t >= off) ? s[t - off] : 0;
        __syncthreads();
        s[t] += u;
        __syncthreads();
    }
    if (t < nblk) blkoff[t] = s[t] - v;
}

__global__ __launch_bounds__(1024) void k_scan_add_g(
    int* __restrict__ out, const int* __restrict__ blkoff, int n)
{
    int i = blockIdx.x * 1024 + threadIdx.x;
    if (i < n) out[i] += blkoff[blockIdx.x];
}

// ---------------------------------------------------------------------------
// Phase A3: partition edges into coarse buckets (line-dense writes).
// chunkOff entries carry a +NE bias from the fused scan; subtract here.
// ---------------------------------------------------------------------------
__global__ __launch_bounds__(256) void kA3(
    const int* __restrict__ src, const int* __restrict__ dst,
    const int* __restrict__ rel, const float* __restrict__ ew,
    const int* __restrict__ chunkOff, int2* __restrict__ pA)
{
    __shared__ int s_c[NBUCK];
    for (int i = threadIdx.x; i < NBUCK; i += 256)
        s_c[i] = chunkOff[i * NCHK + blockIdx.x] - NE;
    __syncthreads();
    int e0 = blockIdx.x * EPC;
    for (int e = e0 + threadIdx.x; e < e0 + EPC; e += 256) {
        int d = dst[e], r = rel[e];
        int pos = atomicAdd(&s_c[d >> 8], 1);
        int2 v;
        v.x = src[e] | (((d & 255) * 4 + r) << 20);
        v.y = __float_as_int(ew[e]);
        pA[pos] = v;
    }
}

// ---------------------------------------------------------------------------
// Phase B: one block per bucket; in-bucket counting sort by seg_local.
// Bucket records cached in LDS on the histogram pass (global fallback for
// tails beyond KB_CAP) -> single global read of pA.
// ---------------------------------------------------------------------------
__global__ __launch_bounds__(256) void kB(
    const int* __restrict__ row_ptr, const int2* __restrict__ pA,
    int2* __restrict__ edat)
{
    __shared__ int2 s_e[KB_CAP];   // 36864 B
    __shared__ int s_c[1024];      //  4096 B
    __shared__ int s_p[256];       //  1024 B
    const int b    = blockIdx.x;
    const int t    = threadIdx.x;
    const int seg0 = b * 1024;
    const int segN = min(1024, NB - seg0);
    const int pbeg = row_ptr[seg0];
    const int pend = row_ptr[seg0 + segN];

    for (int i = t; i < 1024; i += 256) s_c[i] = 0;
    __syncthreads();
    for (int p = pbeg + t; p < pend; p += 256) {
        int2 v = pA[p];
        int idx = p - pbeg;
        if (idx < KB_CAP) s_e[idx] = v;
        atomicAdd(&s_c[((unsigned)v.x) >> 20], 1);
    }
    __syncthreads();

    int c0 = s_c[t * 4], c1 = s_c[t * 4 + 1], c2 = s_c[t * 4 + 2], c3 = s_c[t * 4 + 3];
    int tsum = c0 + c1 + c2 + c3;
    s_p[t] = tsum;
    __syncthreads();
    #pragma unroll
    for (int off = 1; off < 256; off <<= 1) {
        int u = (t >= off) ? s_p[t - off] : 0;
        __syncthreads();
        s_p[t] += u;
        __syncthreads();
    }
    int base = s_p[t] - tsum;
    s_c[t * 4]     = base;
    s_c[t * 4 + 1] = base + c0;
    s_c[t * 4 + 2] = base + c0 + c1;
    s_c[t * 4 + 3] = base + c0 + c1 + c2;
    __syncthreads();

    for (int p = pbeg + t; p < pend; p += 256) {
        int idx = p - pbeg;
        int2 v = (idx < KB_CAP) ? s_e[idx] : pA[p];
        int sl = ((unsigned)v.x) >> 20;
        int pos = atomicAdd(&s_c[sl], 1);
        int2 o; o.x = v.x & 0xFFFFF; o.y = v.y;
        edat[pbeg + pos] = o;
    }
    // 192 zero pad entries: layer kernel over-reads meta up to NE+~160
    if (b == 0 && t < 192) { int2 z; z.x = 0; z.y = 0; edat[NE + t] = z; }
}

// ---------------------------------------------------------------------------
// Weight conversion (transposed bf16)
// ---------------------------------------------------------------------------
__global__ __launch_bounds__(256) void k_cvt_w(
    const float* __restrict__ lin_w, const float* __restrict__ self_w,
    const float* __restrict__ pw, const float* __restrict__ tw,
    unsigned short* __restrict__ WL, unsigned short* __restrict__ WP,
    unsigned short* __restrict__ WT2)
{
    int id = blockIdx.x * 256 + threadIdx.x;   // 3*64*576
    if (id >= 3 * 64 * 576) return;
    int i = id / (64 * 576);
    int r = id % (64 * 576);
    int j = r / 576;
    int k = r % 576;
    if (k < 320) {
        float v = (k < 256) ? lin_w[((size_t)i * 256 + k) * 64 + j]
                            : self_w[((size_t)i * 64 + (k - 256)) * 64 + j];
        WL[((size_t)i * 64 + j) * 320 + k] = f2bf(v);
    } else if (k < 448) {
        int kk = k - 320;
        WP[((size_t)i * 64 + j) * 128 + kk] = f2bf(pw[((size_t)i * 128 + kk) * 64 + j]);
    } else {
        int kk = k - 448;
        WT2[((size_t)i * 64 + j) * 128 + kk] = f2bf(tw[((size_t)i * 128 + kk) * 64 + j]);
    }
}

// ---------------------------------------------------------------------------
// Scalarized edge-stream helpers for k_layer (R11/R13-proven readlane path).
// ---------------------------------------------------------------------------
template<int LBASE>
__device__ __forceinline__ void gather16(
    unsigned short (&g)[16], int2 mb,
    const unsigned short* __restrict__ xb, int lane)
{
    #pragma unroll
    for (int j = 0; j < 16; ++j) {
        unsigned sm = (unsigned)__builtin_amdgcn_readlane(mb.x, LBASE + j);
        g[j] = xb[((size_t)sm << 6) + lane];
    }
}

template<int LBASE, bool CHECK>
__device__ __forceinline__ void consume16(
    const unsigned short (&g)[16], int2 mb, int ebase,
    int E1, int& seg, int& segEnd,
    float& acc, float& dsum,
    const int* sRP, int sbase, int wid, int lane, char* sAp)
{
    #pragma unroll
    for (int j = 0; j < 16; ++j) {
        int eidx = ebase + j;                          // scalar
        if (!CHECK || eidx < E1) {                     // s_cmp path (tail only)
            while (eidx >= segEnd) {                   // flush finished segments
                float u = acc * __builtin_amdgcn_rcpf(dsum + EPS);
                int ln = wid * 8 + (seg >> 2);
                int cb = ((seg & 3) * 64 + lane) * 2;
                *(unsigned short*)(sAp + ln * 640 + (cb ^ ((ln & 7) << 4))) = f2bf(u);
                acc = 0.f; dsum = 0.f;
                ++seg;
                segEnd = __builtin_amdgcn_readfirstlane(sRP[sbase + seg + 1]);
            }
            float w = __int_as_float(__builtin_amdgcn_readlane(mb.y, LBASE + j));
            acc = fmaf(bf2f(g[j]), w, acc);
            dsum += w;
        }
    }
}

template<bool CHECK>
__device__ __forceinline__ void agg_iter64(
    unsigned short (&ga)[16], unsigned short (&gb)[16],
    int2& mb, int e, int E1, int& seg, int& segEnd,
    float& acc, float& dsum, const int* sRP, int sbase,
    int wid, int lane, char* sAp,
    const unsigned short* __restrict__ xb, const int2* __restrict__ edat)
{
    int2 mbn = edat[e + 64 + lane];              // next meta block (padded)
    gather16<16>(gb, mb, xb, lane);
    consume16<0, CHECK>(ga, mb, e, E1, seg, segEnd, acc, dsum, sRP, sbase, wid, lane, sAp);
    gather16<32>(ga, mb, xb, lane);
    consume16<16, CHECK>(gb, mb, e + 16, E1, seg, segEnd, acc, dsum, sRP, sbase, wid, lane, sAp);
    gather16<48>(gb, mb, xb, lane);
    consume16<32, CHECK>(ga, mb, e + 32, E1, seg, segEnd, acc, dsum, sRP, sbase, wid, lane, sAp);
    gather16<0>(ga, mbn, xb, lane);
    consume16<48, CHECK>(gb, mb, e + 48, E1, seg, segEnd, acc, dsum, sRP, sbase, wid, lane, sAp);
    mb = mbn;
}

// ---------------------------------------------------------------------------
// Fused layer: 32 nodes/block, 4 waves (unchanged from R13; at the measured
// per-XCD L2 compulsory-miss floor: dur ~= FETCH / 1.4 TB/s).
// ---------------------------------------------------------------------------
__global__ __launch_bounds__(256, 5) void k_layer(
    const unsigned short* __restrict__ xb,     // layer input bf16 [NN][64]
    const unsigned short* __restrict__ prevb,  // prev hidden bf16 [NN][64]
    const int* __restrict__ row_ptr,
    const int2* __restrict__ edat,
    const unsigned short* __restrict__ WL,     // [64][320]
    const unsigned short* __restrict__ WP,     // [64][128]
    const unsigned short* __restrict__ WT2,    // [64][128]
    const float* __restrict__ lin_b, const float* __restrict__ self_b,
    const float* __restrict__ pb, const float* __restrict__ tb,
    unsigned short* __restrict__ hidb,
    unsigned short* __restrict__ gatedb,
    float* __restrict__ outf,
    int last)
{
    __shared__ __align__(16) unsigned short sA[NPB * 320];  // 20480 B
    __shared__ __align__(16) unsigned short sH[NPB * 128];  //  8192 B
    __shared__ int sRP[NPB * 4 + 1];                        // 129 entries

    const int tid  = threadIdx.x;
    const int lane = tid & 63;
    const int wid  = tid >> 6;
    const int n0   = blockIdx.x * NPB;
    const int bcol = wid * 16 + (lane & 15);
    const int koff2 = (lane >> 4) * 16;
    const int arow = lane & 15;
    const int hi   = lane >> 4;

    if (tid < NPB * 4 + 1) sRP[tid] = row_ptr[n0 * 4 + tid];

    // ---- vectorized staging: 16 B per thread per tile ----
    {
        int r  = tid >> 3;            // 0..31
        int c0 = (tid & 7) * 8;       // 0,8,...,56
        uint4 pv = *(const uint4*)&prevb[(size_t)(n0 + r) * 64 + c0];
        int swz = (r & 7) << 4;
        *(uint4*)((char*)sH + r * 256 + (((64 + c0) * 2) ^ swz)) = pv;
        uint4 xv = *(const uint4*)&xb[(size_t)(n0 + r) * 64 + c0];
        *(uint4*)((char*)sA + r * 640 + (((256 + c0) * 2) ^ swz)) = xv;
    }

    __syncthreads();

    // ---- scalarized edge aggregation (ping-pong, ~16-32 in flight) ----
    const int sbase = wid * 32;
    int E0 = __builtin_amdgcn_readfirstlane(sRP[sbase]);
    int E1 = __builtin_amdgcn_readfirstlane(sRP[sbase + 32]);
    int seg = 0;
    int segEnd = __builtin_amdgcn_readfirstlane(sRP[sbase + 1]);
    float acc = 0.f, dsum = 0.f;

    int2 mb = edat[E0 + lane];       // meta for edges E0..E0+63 (lane j = edge j)
    unsigned short ga[16], gb[16];
    gather16<0>(ga, mb, xb, lane);

    int e = E0;
    for (; e + 64 <= E1; e += 64)    // full blocks: no per-edge E1 guard
        agg_iter64<false>(ga, gb, mb, e, E1, seg, segEnd, acc, dsum,
                          sRP, sbase, wid, lane, (char*)sA, xb, edat);
    if (e < E1)                      // guarded tail
        agg_iter64<true>(ga, gb, mb, e, E1, seg, segEnd, acc, dsum,
                         sRP, sbase, wid, lane, (char*)sA, xb, edat);

    while (seg < 32) {               // trailing flush
        float u = acc * __builtin_amdgcn_rcpf(dsum + EPS);
        int ln = wid * 8 + (seg >> 2);
        int cb = ((seg & 3) * 64 + lane) * 2;
        *(unsigned short*)((char*)sA + ln * 640 + (cb ^ ((ln & 7) << 4))) = f2bf(u);
        acc = 0.f; dsum = 0.f;
        ++seg;
    }

    bfrag8 bwL[10];
    #pragma unroll
    for (int ks = 0; ks < 10; ++ks)
        bwL[ks] = *(const bfrag8*)((const char*)WL + bcol * 640 + ks * 64 + koff2);
    float biasC = lin_b[bcol] + self_b[bcol];
    float pbv = pb[bcol], tbv = tb[bcol];

    __syncthreads();

    // ---- conv MFMA: 2 row-tiles × K=320 ----
    f4acc accC0 = {0.f, 0.f, 0.f, 0.f};
    f4acc accC1 = {0.f, 0.f, 0.f, 0.f};
    #pragma unroll
    for (int ks = 0; ks < 10; ++ks) {
        int co = ks * 64 + koff2;
        bfrag8 a0 = *(const bfrag8*)((const char*)sA + arow * 640 +
                                     (co ^ ((arow & 7) << 4)));
        bfrag8 a1 = *(const bfrag8*)((const char*)sA + (16 + arow) * 640 +
                                     (co ^ (((16 + arow) & 7) << 4)));
        accC0 = __builtin_amdgcn_mfma_f32_16x16x32_bf16(a0, bwL[ks], accC0, 0, 0, 0);
        accC1 = __builtin_amdgcn_mfma_f32_16x16x32_bf16(a1, bwL[ks], accC1, 0, 0, 0);
    }

    bfrag8 bwP[4], bwT[4];
    #pragma unroll
    for (int ks = 0; ks < 4; ++ks) {
        bwP[ks] = *(const bfrag8*)((const char*)WP  + bcol * 256 + ks * 64 + koff2);
        bwT[ks] = *(const bfrag8*)((const char*)WT2 + bcol * 256 + ks * 64 + koff2);
    }

    // sigmoid; stage hid into sH cols 0..63; store hidden bf16
    float hid[8];
    #pragma unroll
    for (int rt = 0; rt < 2; ++rt) {
        #pragma unroll
        for (int q = 0; q < 4; ++q) {
            float o = (rt == 0 ? accC0[q] : accC1[q]) + biasC;
            float h = 1.f / (1.f + __expf(-o));
            hid[rt * 4 + q] = h;
            int row = rt * 16 + hi * 4 + q;
            unsigned short hb = f2bf(h);
            *(unsigned short*)((char*)sH + row * 256 +
                               ((bcol * 2) ^ ((row & 7) << 4))) = hb;
            hidb[(size_t)(n0 + row) * 64 + bcol] = hb;
        }
    }

    __syncthreads();

    // ---- highway MFMA: cat=[hid, prev], K=128, 2 row-tiles ----
    f4acc accP0 = {0.f, 0.f, 0.f, 0.f};
    f4acc accP1 = {0.f, 0.f, 0.f, 0.f};
    f4acc accT0 = {0.f, 0.f, 0.f, 0.f};
    f4acc accT1 = {0.f, 0.f, 0.f, 0.f};
    #pragma unroll
    for (int ks = 0; ks < 4; ++ks) {
        int co = ks * 64 + koff2;
        bfrag8 a0 = *(const bfrag8*)((const char*)sH + arow * 256 +
                                     (co ^ ((arow & 7) << 4)));
        bfrag8 a1 = *(const bfrag8*)((const char*)sH + (16 + arow) * 256 +
                                     (co ^ (((16 + arow) & 7) << 4)));
        accP0 = __builtin_amdgcn_mfma_f32_16x16x32_bf16(a0, bwP[ks], accP0, 0, 0, 0);
        accP1 = __builtin_amdgcn_mfma_f32_16x16x32_bf16(a1, bwP[ks], accP1, 0, 0, 0);
        accT0 = __builtin_amdgcn_mfma_f32_16x16x32_bf16(a0, bwT[ks], accT0, 0, 0, 0);
        accT1 = __builtin_amdgcn_mfma_f32_16x16x32_bf16(a1, bwT[ks], accT1, 0, 0, 0);
    }

    #pragma unroll
    for (int rt = 0; rt < 2; ++rt) {
        #pragma unroll
        for (int q = 0; q < 4; ++q) {
            float ap = (rt == 0 ? accP0[q] : accP1[q]);
            float at = (rt == 0 ? accT0[q] : accT1[q]);
            float proj = fmaxf(ap + pbv, 0.f);
            float gate = 1.f / (1.f + __expf(-(at + tbv)));
            float o = gate * proj + (1.f - gate) * hid[rt * 4 + q];
            int row = rt * 16 + hi * 4 + q;
            if (last) outf[(size_t)(n0 + row) * 64 + bcol] = o;
            else      gatedb[(size_t)(n0 + row) * 64 + bcol] = f2bf(o);
        }
    }
}

// ---------------------------------------------------------------------------
extern "C" void kernel_launch(void* const* d_in, const int* in_sizes, int n_in,
                              void* d_out, int out_size, void* d_ws, size_t ws_size,
                              hipStream_t stream)
{
    const float* node_feat = (const float*)d_in[0];
    const float* ew        = (const float*)d_in[1];
    const float* lin_w     = (const float*)d_in[2];
    const float* lin_b     = (const float*)d_in[3];
    const float* self_w    = (const float*)d_in[4];
    const float* self_b    = (const float*)d_in[5];
    const float* pw        = (const float*)d_in[6];
    const float* pb        = (const float*)d_in[7];
    const float* tw        = (const float*)d_in[8];
    const float* tb        = (const float*)d_in[9];
    const int*   src       = (const int*)d_in[10];
    const int*   dst       = (const int*)d_in[11];
    const int*   rel       = (const int*)d_in[12];
    float* outf = (float*)d_out;

    char* ws = (char*)d_ws;
    // fused-scan buffers: scanout[0..NB] = row_ptr (incl total at NB),
    // scanout+NB = chunkOff (biased by +NE, subtracted in kA3)
    int*            scanout  = (int*)(ws + 0);            // NSCAN*4 = 2000384
    int*            cnt_cat  = (int*)(ws + 2000640);      // NSCAN*4
    int*            blksum   = (int*)(ws + 4001280);      // 512*4
    int*            blkoff   = (int*)(ws + 4003328);      // 512*4
    int2*           pA       = (int2*)(ws + 4005888);     // NE*8
    int2*           edat     = (int2*)(ws + 16805888);    // (NE+192)*8
    unsigned short* nfb      = (unsigned short*)(ws + 29607424);
    unsigned short* hbfA     = (unsigned short*)(ws + 42407424);
    unsigned short* hbfB     = (unsigned short*)(ws + 55207424);
    unsigned short* gbfA     = (unsigned short*)(ws + 68007424);
    unsigned short* gbfB     = (unsigned short*)(ws + 80807424);
    unsigned short* WL       = (unsigned short*)(ws + 93607424);
    unsigned short* WP       = (unsigned short*)(ws + 93607424 + 122880);
    unsigned short* WT2      = (unsigned short*)(ws + 93607424 + 122880 + 49152);

    int* row_ptr  = scanout;
    int* chunkOff = scanout + NB;
    int* cnt_seg  = cnt_cat;
    int* histBC   = cnt_cat + NB;

    // ---- CSR build: deterministic two-phase counting sort, fused scan ----
    hipMemsetAsync(cnt_cat, 0, NSCAN * sizeof(int), stream);
    kA1<<<NCHK, 256, 0, stream>>>(dst, rel, cnt_seg, histBC, node_feat, nfb);
    k_scan_local_g<<<NBLK_FUSED, 1024, 0, stream>>>(cnt_cat, scanout, blksum, NSCAN);
    k_scan_blk_g<<<1, 512, 0, stream>>>(blksum, blkoff, NBLK_FUSED);
    k_scan_add_g<<<NBLK_FUSED, 1024, 0, stream>>>(scanout, blkoff, NSCAN);
    kA3<<<NCHK, 256, 0, stream>>>(src, dst, rel, ew, chunkOff, pA);
    kB<<<NBUCK, 256, 0, stream>>>(row_ptr, pA, edat);

    // weight conversion
    k_cvt_w<<<432, 256, 0, stream>>>(lin_w, self_w, pw, tw, WL, WP, WT2);

    const unsigned short* cur  = nfb;
    const unsigned short* prev = nfb;
    unsigned short* hbuf[3] = { hbfA, hbfB, hbfA };
    unsigned short* gbuf[3] = { gbfA, gbfB, gbfA };

    for (int i = 0; i < 3; ++i) {
        int lastL = (i == 2);
        k_layer<<<NN / NPB, 256, 0, stream>>>(
            cur, prev, row_ptr, edat,
            WL  + (size_t)i * 64 * 320,
            WP  + (size_t)i * 64 * 128,
            WT2 + (size_t)i * 64 * 128,
            lin_b + (size_t)i * 64, self_b + (size_t)i * 64,
            pb + (size_t)i * 64, tb + (size_t)i * 64,
            hbuf[i], gbuf[i], outf, lastL);
        cur  = gbuf[i];
        prev = hbuf[i];
    }
}

// Round 15
// 264.398 us; speedup vs baseline: 1.3971x; 1.2308x over previous
//
#include <hip/hip_runtime.h>

#define NN   100000
#define NE   1600000
#define NB   400000     // NN*4 (dst,rel) segments
#define EPS  1e-10f

#define NPB   32        // nodes per block
#define NCHK  256       // edge chunks (phase A blocks)
#define EPC   6250      // NE / NCHK
#define NBUCK 391       // coarse buckets: dst>>8  (ceil(100000/256))
#define NHBC  (NBUCK * NCHK)   // 100096
#define NBLK_H 98              // ceil(NHBC/1024)
#define KB_CAP 4608            // kB LDS edge cache

typedef __attribute__((ext_vector_type(8))) short bfrag8;
typedef __attribute__((ext_vector_type(4))) float f4acc;

__device__ __forceinline__ unsigned short f2bf(float f) {
    union { float f; unsigned u; } v; v.f = f;
    unsigned r = v.u + 0x7FFF + ((v.u >> 16) & 1);
    return (unsigned short)(r >> 16);
}
__device__ __forceinline__ float bf2f(unsigned short b) {
    union { unsigned u; float f; } v; v.u = ((unsigned)b) << 16;
    return v.f;
}

// ---------------------------------------------------------------------------
// Phase A1: per-(bucket,chunk) histogram (LDS only — no global atomics)
//           + fused node-feature f32 -> bf16 conversion
// ---------------------------------------------------------------------------
__global__ __launch_bounds__(256) void kA1(
    const int* __restrict__ dst,
    int* __restrict__ histBC,
    const float* __restrict__ xf, unsigned short* __restrict__ xb)
{
    __shared__ int s_h[NBUCK];
    for (int i = threadIdx.x; i < NBUCK; i += 256) s_h[i] = 0;
    __syncthreads();
    int e0 = blockIdx.x * EPC;
    for (int e = e0 + threadIdx.x; e < e0 + EPC; e += 256)
        atomicAdd(&s_h[dst[e] >> 8], 1);
    __syncthreads();
    for (int i = threadIdx.x; i < NBUCK; i += 256)
        histBC[i * NCHK + blockIdx.x] = s_h[i];   // bucket-major, fully written

    // fused cvt_x: 8 elems per iteration per thread (independent of above)
    for (int c = blockIdx.x * 256 + threadIdx.x; c < NN * 8; c += NCHK * 256) {
        const float4* s4 = (const float4*)xf + (size_t)c * 2;
        float4 a = s4[0], b = s4[1];
        unsigned short r[8] = { f2bf(a.x), f2bf(a.y), f2bf(a.z), f2bf(a.w),
                                f2bf(b.x), f2bf(b.y), f2bf(b.z), f2bf(b.w) };
        *(uint4*)(xb + (size_t)c * 8) = *(const uint4*)r;
    }
}

// --- generic coalesced 3-phase scan ----------------------------------------
__global__ __launch_bounds__(1024) void k_scan_local_g(
    const int* __restrict__ in, int* __restrict__ out,
    int* __restrict__ blksum, int n)
{
    __shared__ int s[1024];
    int t = threadIdx.x;
    int i = blockIdx.x * 1024 + t;
    int v = (i < n) ? in[i] : 0;
    s[t] = v;
    __syncthreads();
    #pragma unroll
    for (int off = 1; off < 1024; off <<= 1) {
        int u = (t >= off) ? s[t - off] : 0;
        __syncthreads();
        s[t] += u;
        __syncthreads();
    }
    if (i < n) out[i] = s[t] - v;
    if (t == 1023) blksum[blockIdx.x] = s[t];
}

__global__ __launch_bounds__(512) void k_scan_blk_g(
    int* __restrict__ blksum, int* __restrict__ blkoff, int nblk)
{
    __shared__ int s[512];
    int t = threadIdx.x;
    int v = (t < nblk) ? blksum[t] : 0;
    s[t] = v;
    __syncthreads();
    #pragma unroll
    for (int off = 1; off < 512; off <<= 1) {
        int u = (t >= off) ? s[t - off] : 0;
        __syncthreads();
        s[t] += u;
        __syncthreads();
    }
    if (t < nblk) blkoff[t] = s[t] - v;
}

__global__ __launch_bounds__(1024) void k_scan_add_g(
    int* __restrict__ out, const int* __restrict__ blkoff, int n)
{
    int i = blockIdx.x * 1024 + threadIdx.x;
    if (i < n) out[i] += blkoff[blockIdx.x];
}

// ---------------------------------------------------------------------------
// Phase A3: partition edges into coarse buckets (line-dense writes).
// ---------------------------------------------------------------------------
__global__ __launch_bounds__(256) void kA3(
    const int* __restrict__ src, const int* __restrict__ dst,
    const int* __restrict__ rel, const float* __restrict__ ew,
    const int* __restrict__ chunkOff, int2* __restrict__ pA)
{
    __shared__ int s_c[NBUCK];
    for (int i = threadIdx.x; i < NBUCK; i += 256)
        s_c[i] = chunkOff[i * NCHK + blockIdx.x];
    __syncthreads();
    int e0 = blockIdx.x * EPC;
    for (int e = e0 + threadIdx.x; e < e0 + EPC; e += 256) {
        int d = dst[e], r = rel[e];
        int pos = atomicAdd(&s_c[d >> 8], 1);
        int2 v;
        v.x = src[e] | (((d & 255) * 4 + r) << 20);
        v.y = __float_as_int(ew[e]);
        pA[pos] = v;
    }
}

// ---------------------------------------------------------------------------
// Phase B: one block per bucket; in-bucket counting sort by seg_local.
// Also WRITES row_ptr from its local segment scan (replaces the global
// 400K-segment histogram entirely).
// ---------------------------------------------------------------------------
__global__ __launch_bounds__(256) void kB(
    const int* __restrict__ chunkOff, const int2* __restrict__ pA,
    int2* __restrict__ edat, int* __restrict__ row_ptr)
{
    __shared__ int2 s_e[KB_CAP];   // 36864 B
    __shared__ int s_c[1024];      //  4096 B
    __shared__ int s_p[256];       //  1024 B
    const int b    = blockIdx.x;
    const int t    = threadIdx.x;
    const int seg0 = b * 1024;
    const int segN = min(1024, NB - seg0);
    const int pbeg = chunkOff[b * NCHK];
    const int pend = (b + 1 < NBUCK) ? chunkOff[(b + 1) * NCHK] : NE;

    for (int i = t; i < 1024; i += 256) s_c[i] = 0;
    __syncthreads();
    for (int p = pbeg + t; p < pend; p += 256) {
        int2 v = pA[p];
        int idx = p - pbeg;
        if (idx < KB_CAP) s_e[idx] = v;
        atomicAdd(&s_c[((unsigned)v.x) >> 20], 1);
    }
    __syncthreads();

    int c0 = s_c[t * 4], c1 = s_c[t * 4 + 1], c2 = s_c[t * 4 + 2], c3 = s_c[t * 4 + 3];
    int tsum = c0 + c1 + c2 + c3;
    s_p[t] = tsum;
    __syncthreads();
    #pragma unroll
    for (int off = 1; off < 256; off <<= 1) {
        int u = (t >= off) ? s_p[t - off] : 0;
        __syncthreads();
        s_p[t] += u;
        __syncthreads();
    }
    int base = s_p[t] - tsum;
    s_c[t * 4]     = base;
    s_c[t * 4 + 1] = base + c0;
    s_c[t * 4 + 2] = base + c0 + c1;
    s_c[t * 4 + 3] = base + c0 + c1 + c2;
    __syncthreads();

    // write row_ptr from the (still unmutated) exclusive offsets
    for (int i = t; i < segN; i += 256)
        row_ptr[seg0 + i] = pbeg + s_c[i];
    if (b == NBUCK - 1 && t == 0) row_ptr[NB] = NE;
    __syncthreads();

    // scatter (mutates s_c)
    for (int p = pbeg + t; p < pend; p += 256) {
        int idx = p - pbeg;
        int2 v = (idx < KB_CAP) ? s_e[idx] : pA[p];
        int sl = ((unsigned)v.x) >> 20;
        int pos = atomicAdd(&s_c[sl], 1);
        int2 o; o.x = v.x & 0xFFFFF; o.y = v.y;
        edat[pbeg + pos] = o;
    }
    // 192 zero pad entries: layer kernel over-reads meta up to NE+~160
    if (b == 0 && t < 192) { int2 z; z.x = 0; z.y = 0; edat[NE + t] = z; }
}

// ---------------------------------------------------------------------------
// Weight conversion (transposed bf16)
// ---------------------------------------------------------------------------
__global__ __launch_bounds__(256) void k_cvt_w(
    const float* __restrict__ lin_w, const float* __restrict__ self_w,
    const float* __restrict__ pw, const float* __restrict__ tw,
    unsigned short* __restrict__ WL, unsigned short* __restrict__ WP,
    unsigned short* __restrict__ WT2)
{
    int id = blockIdx.x * 256 + threadIdx.x;   // 3*64*576
    if (id >= 3 * 64 * 576) return;
    int i = id / (64 * 576);
    int r = id % (64 * 576);
    int j = r / 576;
    int k = r % 576;
    if (k < 320) {
        float v = (k < 256) ? lin_w[((size_t)i * 256 + k) * 64 + j]
                            : self_w[((size_t)i * 64 + (k - 256)) * 64 + j];
        WL[((size_t)i * 64 + j) * 320 + k] = f2bf(v);
    } else if (k < 448) {
        int kk = k - 320;
        WP[((size_t)i * 64 + j) * 128 + kk] = f2bf(pw[((size_t)i * 128 + kk) * 64 + j]);
    } else {
        int kk = k - 448;
        WT2[((size_t)i * 64 + j) * 128 + kk] = f2bf(tw[((size_t)i * 128 + kk) * 64 + j]);
    }
}

// ---------------------------------------------------------------------------
// Scalarized edge-stream helpers for k_layer (R11/R13-proven readlane path).
// ---------------------------------------------------------------------------
template<int LBASE>
__device__ __forceinline__ void gather16(
    unsigned short (&g)[16], int2 mb,
    const unsigned short* __restrict__ xb, int lane)
{
    #pragma unroll
    for (int j = 0; j < 16; ++j) {
        unsigned sm = (unsigned)__builtin_amdgcn_readlane(mb.x, LBASE + j);
        g[j] = xb[((size_t)sm << 6) + lane];
    }
}

template<int LBASE, bool CHECK>
__device__ __forceinline__ void consume16(
    const unsigned short (&g)[16], int2 mb, int ebase,
    int E1, int& seg, int& segEnd,
    float& acc, float& dsum,
    const int* sRP, int sbase, int wid, int lane, char* sAp)
{
    #pragma unroll
    for (int j = 0; j < 16; ++j) {
        int eidx = ebase + j;                          // scalar
        if (!CHECK || eidx < E1) {                     // s_cmp path (tail only)
            while (eidx >= segEnd) {                   // flush finished segments
                float u = acc * __builtin_amdgcn_rcpf(dsum + EPS);
                int ln = wid * 8 + (seg >> 2);
                int cb = ((seg & 3) * 64 + lane) * 2;
                *(unsigned short*)(sAp + ln * 640 + (cb ^ ((ln & 7) << 4))) = f2bf(u);
                acc = 0.f; dsum = 0.f;
                ++seg;
                segEnd = __builtin_amdgcn_readfirstlane(sRP[sbase + seg + 1]);
            }
            float w = __int_as_float(__builtin_amdgcn_readlane(mb.y, LBASE + j));
            acc = fmaf(bf2f(g[j]), w, acc);
            dsum += w;
        }
    }
}

template<bool CHECK>
__device__ __forceinline__ void agg_iter64(
    unsigned short (&ga)[16], unsigned short (&gb)[16],
    int2& mb, int e, int E1, int& seg, int& segEnd,
    float& acc, float& dsum, const int* sRP, int sbase,
    int wid, int lane, char* sAp,
    const unsigned short* __restrict__ xb, const int2* __restrict__ edat)
{
    int2 mbn = edat[e + 64 + lane];              // next meta block (padded)
    gather16<16>(gb, mb, xb, lane);
    consume16<0, CHECK>(ga, mb, e, E1, seg, segEnd, acc, dsum, sRP, sbase, wid, lane, sAp);
    gather16<32>(ga, mb, xb, lane);
    consume16<16, CHECK>(gb, mb, e + 16, E1, seg, segEnd, acc, dsum, sRP, sbase, wid, lane, sAp);
    gather16<48>(gb, mb, xb, lane);
    consume16<32, CHECK>(ga, mb, e + 32, E1, seg, segEnd, acc, dsum, sRP, sbase, wid, lane, sAp);
    gather16<0>(ga, mbn, xb, lane);
    consume16<48, CHECK>(gb, mb, e + 48, E1, seg, segEnd, acc, dsum, sRP, sbase, wid, lane, sAp);
    mb = mbn;
}

// ---------------------------------------------------------------------------
// Fused layer: 32 nodes/block, 4 waves (unchanged from R13; at the measured
// per-XCD L2 compulsory-miss floor: dur ~= FETCH / 1.4 TB/s).
// ---------------------------------------------------------------------------
__global__ __launch_bounds__(256, 5) void k_layer(
    const unsigned short* __restrict__ xb,     // layer input bf16 [NN][64]
    const unsigned short* __restrict__ prevb,  // prev hidden bf16 [NN][64]
    const int* __restrict__ row_ptr,
    const int2* __restrict__ edat,
    const unsigned short* __restrict__ WL,     // [64][320]
    const unsigned short* __restrict__ WP,     // [64][128]
    const unsigned short* __restrict__ WT2,    // [64][128]
    const float* __restrict__ lin_b, const float* __restrict__ self_b,
    const float* __restrict__ pb, const float* __restrict__ tb,
    unsigned short* __restrict__ hidb,
    unsigned short* __restrict__ gatedb,
    float* __restrict__ outf,
    int last)
{
    __shared__ __align__(16) unsigned short sA[NPB * 320];  // 20480 B
    __shared__ __align__(16) unsigned short sH[NPB * 128];  //  8192 B
    __shared__ int sRP[NPB * 4 + 1];                        // 129 entries

    const int tid  = threadIdx.x;
    const int lane = tid & 63;
    const int wid  = tid >> 6;
    const int n0   = blockIdx.x * NPB;
    const int bcol = wid * 16 + (lane & 15);
    const int koff2 = (lane >> 4) * 16;
    const int arow = lane & 15;
    const int hi   = lane >> 4;

    if (tid < NPB * 4 + 1) sRP[tid] = row_ptr[n0 * 4 + tid];

    // ---- vectorized staging: 16 B per thread per tile ----
    {
        int r  = tid >> 3;            // 0..31
        int c0 = (tid & 7) * 8;       // 0,8,...,56
        uint4 pv = *(const uint4*)&prevb[(size_t)(n0 + r) * 64 + c0];
        int swz = (r & 7) << 4;
        *(uint4*)((char*)sH + r * 256 + (((64 + c0) * 2) ^ swz)) = pv;
        uint4 xv = *(const uint4*)&xb[(size_t)(n0 + r) * 64 + c0];
        *(uint4*)((char*)sA + r * 640 + (((256 + c0) * 2) ^ swz)) = xv;
    }

    __syncthreads();

    // ---- scalarized edge aggregation (ping-pong, ~16-32 in flight) ----
    const int sbase = wid * 32;
    int E0 = __builtin_amdgcn_readfirstlane(sRP[sbase]);
    int E1 = __builtin_amdgcn_readfirstlane(sRP[sbase + 32]);
    int seg = 0;
    int segEnd = __builtin_amdgcn_readfirstlane(sRP[sbase + 1]);
    float acc = 0.f, dsum = 0.f;

    int2 mb = edat[E0 + lane];       // meta for edges E0..E0+63 (lane j = edge j)
    unsigned short ga[16], gb[16];
    gather16<0>(ga, mb, xb, lane);

    int e = E0;
    for (; e + 64 <= E1; e += 64)    // full blocks: no per-edge E1 guard
        agg_iter64<false>(ga, gb, mb, e, E1, seg, segEnd, acc, dsum,
                          sRP, sbase, wid, lane, (char*)sA, xb, edat);
    if (e < E1)                      // guarded tail
        agg_iter64<true>(ga, gb, mb, e, E1, seg, segEnd, acc, dsum,
                         sRP, sbase, wid, lane, (char*)sA, xb, edat);

    while (seg < 32) {               // trailing flush
        float u = acc * __builtin_amdgcn_rcpf(dsum + EPS);
        int ln = wid * 8 + (seg >> 2);
        int cb = ((seg & 3) * 64 + lane) * 2;
        *(unsigned short*)((char*)sA + ln * 640 + (cb ^ ((ln & 7) << 4))) = f2bf(u);
        acc = 0.f; dsum = 0.f;
        ++seg;
    }

    bfrag8 bwL[10];
    #pragma unroll
    for (int ks = 0; ks < 10; ++ks)
        bwL[ks] = *(const bfrag8*)((const char*)WL + bcol * 640 + ks * 64 + koff2);
    float biasC = lin_b[bcol] + self_b[bcol];
    float pbv = pb[bcol], tbv = tb[bcol];

    __syncthreads();

    // ---- conv MFMA: 2 row-tiles × K=320 ----
    f4acc accC0 = {0.f, 0.f, 0.f, 0.f};
    f4acc accC1 = {0.f, 0.f, 0.f, 0.f};
    #pragma unroll
    for (int ks = 0; ks < 10; ++ks) {
        int co = ks * 64 + koff2;
        bfrag8 a0 = *(const bfrag8*)((const char*)sA + arow * 640 +
                                     (co ^ ((arow & 7) << 4)));
        bfrag8 a1 = *(const bfrag8*)((const char*)sA + (16 + arow) * 640 +
                                     (co ^ (((16 + arow) & 7) << 4)));
        accC0 = __builtin_amdgcn_mfma_f32_16x16x32_bf16(a0, bwL[ks], accC0, 0, 0, 0);
        accC1 = __builtin_amdgcn_mfma_f32_16x16x32_bf16(a1, bwL[ks], accC1, 0, 0, 0);
    }

    bfrag8 bwP[4], bwT[4];
    #pragma unroll
    for (int ks = 0; ks < 4; ++ks) {
        bwP[ks] = *(const bfrag8*)((const char*)WP  + bcol * 256 + ks * 64 + koff2);
        bwT[ks] = *(const bfrag8*)((const char*)WT2 + bcol * 256 + ks * 64 + koff2);
    }

    // sigmoid; stage hid into sH cols 0..63; store hidden bf16
    float hid[8];
    #pragma unroll
    for (int rt = 0; rt < 2; ++rt) {
        #pragma unroll
        for (int q = 0; q < 4; ++q) {
            float o = (rt == 0 ? accC0[q] : accC1[q]) + biasC;
            float h = 1.f / (1.f + __expf(-o));
            hid[rt * 4 + q] = h;
            int row = rt * 16 + hi * 4 + q;
            unsigned short hb = f2bf(h);
            *(unsigned short*)((char*)sH + row * 256 +
                               ((bcol * 2) ^ ((row & 7) << 4))) = hb;
            hidb[(size_t)(n0 + row) * 64 + bcol] = hb;
        }
    }

    __syncthreads();

    // ---- highway MFMA: cat=[hid, prev], K=128, 2 row-tiles ----
    f4acc accP0 = {0.f, 0.f, 0.f, 0.f};
    f4acc accP1 = {0.f, 0.f, 0.f, 0.f};
    f4acc accT0 = {0.f, 0.f, 0.f, 0.f};
    f4acc accT1 = {0.f, 0.f, 0.f, 0.f};
    #pragma unroll
    for (int ks = 0; ks < 4; ++ks) {
        int co = ks * 64 + koff2;
        bfrag8 a0 = *(const bfrag8*)((const char*)sH + arow * 256 +
                                     (co ^ ((arow & 7) << 4)));
        bfrag8 a1 = *(const bfrag8*)((const char*)sH + (16 + arow) * 256 +
                                     (co ^ (((16 + arow) & 7) << 4)));
        accP0 = __builtin_amdgcn_mfma_f32_16x16x32_bf16(a0, bwP[ks], accP0, 0, 0, 0);
        accP1 = __builtin_amdgcn_mfma_f32_16x16x32_bf16(a1, bwP[ks], accP1, 0, 0, 0);
        accT0 = __builtin_amdgcn_mfma_f32_16x16x32_bf16(a0, bwT[ks], accT0, 0, 0, 0);
        accT1 = __builtin_amdgcn_mfma_f32_16x16x32_bf16(a1, bwT[ks], accT1, 0, 0, 0);
    }

    #pragma unroll
    for (int rt = 0; rt < 2; ++rt) {
        #pragma unroll
        for (int q = 0; q < 4; ++q) {
            float ap = (rt == 0 ? accP0[q] : accP1[q]);
            float at = (rt == 0 ? accT0[q] : accT1[q]);
            float proj = fmaxf(ap + pbv, 0.f);
            float gate = 1.f / (1.f + __expf(-(at + tbv)));
            float o = gate * proj + (1.f - gate) * hid[rt * 4 + q];
            int row = rt * 16 + hi * 4 + q;
            if (last) outf[(size_t)(n0 + row) * 64 + bcol] = o;
            else      gatedb[(size_t)(n0 + row) * 64 + bcol] = f2bf(o);
        }
    }
}

// ---------------------------------------------------------------------------
extern "C" void kernel_launch(void* const* d_in, const int* in_sizes, int n_in,
                              void* d_out, int out_size, void* d_ws, size_t ws_size,
                              hipStream_t stream)
{
    const float* node_feat = (const float*)d_in[0];
    const float* ew        = (const float*)d_in[1];
    const float* lin_w     = (const float*)d_in[2];
    const float* lin_b     = (const float*)d_in[3];
    const float* self_w    = (const float*)d_in[4];
    const float* self_b    = (const float*)d_in[5];
    const float* pw        = (const float*)d_in[6];
    const float* pb        = (const float*)d_in[7];
    const float* tw        = (const float*)d_in[8];
    const float* tb        = (const float*)d_in[9];
    const int*   src       = (const int*)d_in[10];
    const int*   dst       = (const int*)d_in[11];
    const int*   rel       = (const int*)d_in[12];
    float* outf = (float*)d_out;

    char* ws = (char*)d_ws;
    int*            row_ptr  = (int*)(ws + 0);            // (NB+1)*4
    int*            chunkOff = (int*)(ws + 1600256);      // NHBC*4
    int*            histBC   = (int*)(ws + 2000640);      // NHBC*4
    int*            blksum   = (int*)(ws + 2401024);      // 512*4
    int*            blkoff   = (int*)(ws + 2403072);      // 512*4
    int2*           pA       = (int2*)(ws + 2405376);     // NE*8
    int2*           edat     = (int2*)(ws + 15205376);    // (NE+192)*8
    unsigned short* nfb      = (unsigned short*)(ws + 28007424);
    unsigned short* hbfA     = (unsigned short*)(ws + 40807424);
    unsigned short* hbfB     = (unsigned short*)(ws + 53607424);
    unsigned short* gbfA     = (unsigned short*)(ws + 66407424);
    unsigned short* gbfB     = (unsigned short*)(ws + 79207424);
    unsigned short* WL       = (unsigned short*)(ws + 92007424);
    unsigned short* WP       = (unsigned short*)(ws + 92007424 + 122880);
    unsigned short* WT2      = (unsigned short*)(ws + 92007424 + 122880 + 49152);

    // ---- CSR build: no global histogram atomics, no memset ----
    kA1<<<NCHK, 256, 0, stream>>>(dst, histBC, node_feat, nfb);
    k_scan_local_g<<<NBLK_H, 1024, 0, stream>>>(histBC, chunkOff, blksum, NHBC);
    k_scan_blk_g<<<1, 512, 0, stream>>>(blksum, blkoff, NBLK_H);
    k_scan_add_g<<<NBLK_H, 1024, 0, stream>>>(chunkOff, blkoff, NHBC);
    kA3<<<NCHK, 256, 0, stream>>>(src, dst, rel, ew, chunkOff, pA);
    kB<<<NBUCK, 256, 0, stream>>>(chunkOff, pA, edat, row_ptr);

    // weight conversion
    k_cvt_w<<<432, 256, 0, stream>>>(lin_w, self_w, pw, tw, WL, WP, WT2);

    const unsigned short* cur  = nfb;
    const unsigned short* prev = nfb;
    unsigned short* hbuf[3] = { hbfA, hbfB, hbfA };
    unsigned short* gbuf[3] = { gbfA, gbfB, gbfA };

    for (int i = 0; i < 3; ++i) {
        int lastL = (i == 2);
        k_layer<<<NN / NPB, 256, 0, stream>>>(
            cur, prev, row_ptr, edat,
            WL  + (size_t)i * 64 * 320,
            WP  + (size_t)i * 64 * 128,
            WT2 + (size_t)i * 64 * 128,
            lin_b + (size_t)i * 64, self_b + (size_t)i * 64,
            pb + (size_t)i * 64, tb + (size_t)i * 64,
            hbuf[i], gbuf[i], outf, lastL);
        cur  = gbuf[i];
        prev = hbuf[i];
    }
}